// Round 3
// baseline (621.699 us; speedup 1.0000x reference)
//
#include <hip/hip_runtime.h>
#include <math.h>

#define BATCH 8
#define NPRI  4096
#define TOPK  200

typedef unsigned long long u64;
typedef unsigned int u32;

#define WS_SOA (BATCH * NPRI)  // floats per SoA array
#define NTASK  (64 * 8 * 16)   // level a (64) x img (8) x wordgroup g (16)
#define PRODUCER_BLOCKS 512

// workspace layout (bytes):
//   [0, 6*WS_SOA*4)                      : SoA x1,y1,x2,y2,area,score (sorted order)
//   [MASK_OFF, MASK_OFF+16MB)            : mask words, idx = ((b*64+w)<<12) + i
//   [FLAGS_OFF, +4KB)                    : [0]=task ctr, [1]=done_imgs, [2..9]=stop[8],
//                                          [16..16+512)=done[img][level]
#define MASK_OFF  ((size_t)6 * WS_SOA * sizeof(float))
#define FLAGS_OFF (MASK_OFF + (size_t)BATCH * 64 * NPRI * sizeof(u64))

// correctly-rounded f32 exp via f64 (matches numpy float32 exp bit-exactly)
__device__ __forceinline__ float exp_f32_cr(float x) { return (float)exp((double)x); }

__device__ __forceinline__ u64 shflx64(u64 v, int m) {
  u32 lo = (u32)__shfl_xor((int)(u32)v, m);
  u32 hi = (u32)__shfl_xor((int)(u32)(v >> 32), m);
  return ((u64)hi << 32) | lo;
}

__device__ __forceinline__ void cmpex(u64& x, u64& y, bool up) {
  if ((x > y) == up) { u64 t = x; x = y; y = t; }
}

// ---------------------------------------------------------------------------
// K1: scores + stable sort (register/shfl/LDS hybrid bitonic) + decode -> SoA
// ---------------------------------------------------------------------------
__global__ __launch_bounds__(1024) void sort_decode_kernel(
    const float* __restrict__ loc, const float* __restrict__ conf,
    const float* __restrict__ prior, float* __restrict__ ws) {
  __shared__ u64 sk[NPRI];  // 32 KB
  const int b = blockIdx.x, t = threadIdx.x;
  const int lane = t & 63;
  const int p0 = t << 2;

  u64 r0, r1, r2, r3;
  {
    const float4* cf4 = (const float4*)conf;
    int base = (b * NPRI + p0) >> 1;
    float4 cA = cf4[base], cB = cf4[base + 1];
    float c0[4] = {cA.x, cA.z, cB.x, cB.z};
    float c1[4] = {cA.y, cA.w, cB.y, cB.w};
    u64 rr[4];
#pragma unroll
    for (int q = 0; q < 4; ++q) {
      float m = fmaxf(c0[q], c1[q]);
      float e0 = exp_f32_cr(__fsub_rn(c0[q], m));
      float e1 = exp_f32_cr(__fsub_rn(c1[q], m));
      float s = __fdiv_rn(e1, __fadd_rn(e0, e1));
      rr[q] = ((u64)(~__float_as_uint(s)) << 32) | (u32)(p0 + q);
    }
    r0 = rr[0]; r1 = rr[1]; r2 = rr[2]; r3 = rr[3];
  }

  for (int k = 2; k <= NPRI; k <<= 1) {
    if (k >= 512) {
      sk[p0 + 0] = r0; sk[p0 + 1] = r1; sk[p0 + 2] = r2; sk[p0 + 3] = r3;
      __syncthreads();
      for (int j = k >> 1; j >= 256; j >>= 1) {
#pragma unroll
        for (int e = 0; e < 4; ++e) {
          int i = t + (e << 10);
          int ixj = i ^ j;
          if (ixj > i) {
            u64 A = sk[i], B = sk[ixj];
            bool up = ((i & k) == 0);
            if ((A > B) == up) { sk[i] = B; sk[ixj] = A; }
          }
        }
        __syncthreads();
      }
      r0 = sk[p0 + 0]; r1 = sk[p0 + 1]; r2 = sk[p0 + 2]; r3 = sk[p0 + 3];
    }
    {
      bool up = ((p0 & k) == 0);
      for (int j = ((k >> 1) > 128 ? 128 : (k >> 1)); j >= 4; j >>= 1) {
        int m = j >> 2;
        bool lower = ((lane & m) == 0);
        bool takeMin = (lower == up);
        u64 o0 = shflx64(r0, m), o1 = shflx64(r1, m);
        u64 o2 = shflx64(r2, m), o3 = shflx64(r3, m);
        r0 = takeMin ? (r0 < o0 ? r0 : o0) : (r0 > o0 ? r0 : o0);
        r1 = takeMin ? (r1 < o1 ? r1 : o1) : (r1 > o1 ? r1 : o1);
        r2 = takeMin ? (r2 < o2 ? r2 : o2) : (r2 > o2 ? r2 : o2);
        r3 = takeMin ? (r3 < o3 ? r3 : o3) : (r3 > o3 ? r3 : o3);
      }
    }
    if (k >= 4) {
      bool up = ((p0 & k) == 0);
      cmpex(r0, r2, up); cmpex(r1, r3, up);
    }
    if (k == 2) {
      cmpex(r0, r1, true); cmpex(r2, r3, false);
    } else {
      bool up = ((p0 & k) == 0);
      cmpex(r0, r1, up); cmpex(r2, r3, up);
    }
  }

  float* sx1 = ws;
  float* sy1 = ws + 1 * WS_SOA;
  float* sx2 = ws + 2 * WS_SOA;
  float* sy2 = ws + 3 * WS_SOA;
  float* sar = ws + 4 * WS_SOA;
  float* ssc = ws + 5 * WS_SOA;

  u64 keys[4] = {r0, r1, r2, r3};
#pragma unroll
  for (int q = 0; q < 4; ++q) {
    u64 key = keys[q];
    int i = (int)(u32)key;
    float s = __uint_as_float(~(u32)(key >> 32));
    float4 l = ((const float4*)loc)[b * NPRI + i];
    float4 p = ((const float4*)prior)[i];
    float cx = __fadd_rn(p.x, __fmul_rn(__fmul_rn(l.x, 0.1f), p.z));
    float cy = __fadd_rn(p.y, __fmul_rn(__fmul_rn(l.y, 0.1f), p.w));
    float w  = __fmul_rn(p.z, exp_f32_cr(__fmul_rn(l.z, 0.2f)));
    float h  = __fmul_rn(p.w, exp_f32_cr(__fmul_rn(l.w, 0.2f)));
    float hw = __fmul_rn(w, 0.5f), hh = __fmul_rn(h, 0.5f);
    float x1 = __fsub_rn(cx, hw), x2 = __fadd_rn(cx, hw);
    float y1 = __fsub_rn(cy, hh), y2 = __fadd_rn(cy, hh);
    int o = b * NPRI + p0 + q;
    sx1[o] = x1; sy1[o] = y1; sx2[o] = x2; sy2[o] = y2;
    sar[o] = __fmul_rn(__fsub_rn(x2, x1), __fsub_rn(y2, y1));
    ssc[o] = s;
  }
}

// ---------------------------------------------------------------------------
// K2: fused producer/consumer. blockIdx 0..7 = consumers (1 wave each),
// rest = producers (4 waves, dynamic task pull, chunk-major order).
// Producers never wait on consumers -> deadlock-free under any scheduling.
// ---------------------------------------------------------------------------
__global__ __launch_bounds__(256) void fused_nms_kernel(
    const float* __restrict__ ws, u64* __restrict__ mask, int* __restrict__ flags,
    float* __restrict__ out) {
  const int bid = blockIdx.x;
  const float* sx1 = ws;
  const float* sy1 = ws + 1 * WS_SOA;
  const float* sx2 = ws + 2 * WS_SOA;
  const float* sy2 = ws + 3 * WS_SOA;
  const float* sar = ws + 4 * WS_SOA;
  const float* ssc = ws + 5 * WS_SOA;
  int* taskc = flags;
  int* dimg  = flags + 1;
  int* stopf = flags + 2;   // [8]
  int* done  = flags + 16;  // [8][64]

  if (bid < BATCH) {
    // ---------------- consumer: greedy scan for image b ----------------
    if (threadIdx.x >= 64) return;
    __shared__ int klist[TOPK];
    const int b = bid, lane = threadIdx.x;
    const u64* mb = mask + ((u64)b << 18);
    u64 removed = 0;
    int cnt = 0;

    for (int c = 0; c < 64; ++c) {
      // wait until level c fully produced (16 wordgroup-waves)
      while (__hip_atomic_load(&done[b * 64 + c], __ATOMIC_RELAXED,
                               __HIP_MEMORY_SCOPE_AGENT) < 16)
        __builtin_amdgcn_s_sleep(2);
      __threadfence();  // acquire: invalidate stale cache before tile reads

      float sc = ssc[b * NPRI + c * 64 + lane];
      u64 vm = __ballot(sc > 0.01f);
      if (vm == 0) break;  // sorted desc: nothing valid beyond here

      u64 Dreg = mb[((u64)c << 12) + c * 64 + lane];  // diag word (w=c, row lane)
      u64 rw = __shfl(removed, c);
      u64 ck = 0;
      for (int g = 0; g < 64; g += 8) {
        u64 d[8];
#pragma unroll
        for (int q = 0; q < 8; ++q) d[q] = __shfl(Dreg, g + q);
#pragma unroll
        for (int q = 0; q < 8; ++q) {
          u64 kbit = ((vm & ~rw) >> (g + q)) & 1ull;
          rw |= d[q] & (0ull - kbit);
          ck |= kbit << (g + q);
        }
      }

      // apply kept rows: predicated gather of this lane's word column.
      // words w=lane<c are garbage (never produced) but only pollute removed
      // words for chunks already processed -> never read again.
      const u64* col = mb + ((u64)lane << 12) + c * 64;
      u64 acc = 0;
#pragma unroll
      for (int bb = 0; bb < 64; ++bb) {
        u64 m = col[bb];
        acc |= (((ck >> bb) & 1ull) ? m : 0ull);
      }
      removed |= acc;

      if ((ck >> lane) & 1ull) {
        int pos = cnt + __popcll(ck & ((1ull << lane) - 1ull));
        if (pos < TOPK) klist[pos] = c * 64 + lane;
      }
      cnt += __popcll(ck);
      if (cnt >= TOPK) break;
    }

    if (lane == 0) {
      __hip_atomic_store(&stopf[b], 1, __ATOMIC_RELAXED, __HIP_MEMORY_SCOPE_AGENT);
      __hip_atomic_fetch_add(dimg, 1, __ATOMIC_RELAXED, __HIP_MEMORY_SCOPE_AGENT);
    }
    __builtin_amdgcn_wave_barrier();

    int total = cnt < TOPK ? cnt : TOPK;
    for (int p = lane; p < total; p += 64) {
      int i = klist[p];
      int o = b * NPRI + i;
      float* dst = out + (((size_t)b * 2 + 1) * TOPK + p) * 5;
      dst[0] = ssc[o]; dst[1] = sx1[o]; dst[2] = sy1[o]; dst[3] = sx2[o]; dst[4] = sy2[o];
    }
    return;
  }

  // ---------------- producer: dynamic (level, img, wordgroup) tasks ----------
  __shared__ float4 jbox[4][64];
  __shared__ float jarea[4][64];
  const int t = threadIdx.x, lane = t & 63, wv = t >> 6;
  const double M = 0.5 * ((double)0.45f + (double)__uint_as_float(0x3EE66667u));

  for (;;) {
    if (__hip_atomic_load(dimg, __ATOMIC_RELAXED, __HIP_MEMORY_SCOPE_AGENT) == 8)
      break;  // all consumers finished: nobody needs the remaining tiles
    int tau = 0;
    if (lane == 0) tau = atomicAdd(taskc, 1);
    tau = __shfl(tau, 0);
    if (tau >= NTASK) break;

    const int a = tau >> 7, img = (tau >> 4) & 7, g = tau & 15;
    const int w0 = a + 4 * g;
    bool skip = (w0 >= 64) ||
                (__hip_atomic_load(&stopf[img], __ATOMIC_RELAXED,
                                   __HIP_MEMORY_SCOPE_AGENT) != 0);
    if (!skip) {
      const int i = a * 64 + lane, o = img * NPRI + i;
      const float ix1 = sx1[o], iy1 = sy1[o], ix2 = sx2[o], iy2 = sy2[o], iar = sar[o];
      const int nw = (64 - w0) < 4 ? (64 - w0) : 4;
#pragma unroll 1
      for (int s = 0; s < nw; ++s) {
        const int w = w0 + s;
        const int jo = img * NPRI + w * 64 + lane;
        jbox[wv][lane] = make_float4(sx1[jo], sy1[jo], sx2[jo], sy2[jo]);
        jarea[wv][lane] = sar[jo];
        __builtin_amdgcn_wave_barrier();

        u64 bits = 0;
#pragma unroll 8
        for (int jj = 0; jj < 64; ++jj) {
          float4 jb = jbox[wv][jj];
          float bar = jarea[wv][jj];
          float iw = fmaxf(__fsub_rn(fminf(ix2, jb.z), fmaxf(ix1, jb.x)), 0.0f);
          float ih = fmaxf(__fsub_rn(fminf(iy2, jb.w), fmaxf(iy1, jb.y)), 0.0f);
          float inter = __fmul_rn(iw, ih);
          float uni   = __fsub_rn(__fadd_rn(iar, bar), inter);
          if ((double)inter > M * (double)uni) bits |= (1ull << jj);
        }
        mask[(((u64)(img * 64 + w)) << 12) + (u32)i] = bits;
        __builtin_amdgcn_wave_barrier();
      }
      __threadfence();  // release: flush tile stores before publishing
    }
    if (lane == 0) atomicAdd(&done[img * 64 + a], 1);
  }
}

// ---------------------------------------------------------------------------
extern "C" void kernel_launch(void* const* d_in, const int* in_sizes, int n_in,
                              void* d_out, int out_size, void* d_ws, size_t ws_size,
                              hipStream_t stream) {
  const float* loc   = (const float*)d_in[0];
  const float* conf  = (const float*)d_in[1];
  const float* prior = (const float*)d_in[2];
  float* out = (float*)d_out;
  float* ws  = (float*)d_ws;
  u64*   msk = (u64*)((char*)d_ws + MASK_OFF);
  int*   flg = (int*)((char*)d_ws + FLAGS_OFF);

  hipMemsetAsync(d_out, 0, (size_t)out_size * sizeof(float), stream);
  hipMemsetAsync(flg, 0, 4096, stream);
  sort_decode_kernel<<<BATCH, 1024, 0, stream>>>(loc, conf, prior, ws);
  fused_nms_kernel<<<BATCH + PRODUCER_BLOCKS, 256, 0, stream>>>(ws, msk, flg, out);
}

// Round 4
// 115.329 us; speedup vs baseline: 5.3907x; 5.3907x over previous
//
#include <hip/hip_runtime.h>
#include <math.h>

#define BATCH 8
#define NPRI  4096
#define TOPK  200

typedef unsigned long long u64;
typedef unsigned int u32;

#define WS_SOA (BATCH * NPRI)  // floats per SoA array

// correctly-rounded f32 exp via f64 (matches numpy float32 exp bit-exactly)
__device__ __forceinline__ float exp_f32_cr(float x) { return (float)exp((double)x); }

__device__ __forceinline__ u64 shflx64(u64 v, int m) {
  u32 lo = (u32)__shfl_xor((int)(u32)v, m);
  u32 hi = (u32)__shfl_xor((int)(u32)(v >> 32), m);
  return ((u64)hi << 32) | lo;
}

__device__ __forceinline__ void cmpex(u64& x, u64& y, bool up) {
  if ((x > y) == up) { u64 t = x; x = y; y = t; }
}

// ---------------------------------------------------------------------------
// K1: scores + stable sort (register/shfl/LDS hybrid bitonic) + decode -> SoA
// ---------------------------------------------------------------------------
__global__ __launch_bounds__(1024) void sort_decode_kernel(
    const float* __restrict__ loc, const float* __restrict__ conf,
    const float* __restrict__ prior, float* __restrict__ ws) {
  __shared__ u64 sk[NPRI];  // 32 KB
  const int b = blockIdx.x, t = threadIdx.x;
  const int lane = t & 63;
  const int p0 = t << 2;

  u64 r0, r1, r2, r3;
  {
    const float4* cf4 = (const float4*)conf;
    int base = (b * NPRI + p0) >> 1;
    float4 cA = cf4[base], cB = cf4[base + 1];
    float c0[4] = {cA.x, cA.z, cB.x, cB.z};
    float c1[4] = {cA.y, cA.w, cB.y, cB.w};
    u64 rr[4];
#pragma unroll
    for (int q = 0; q < 4; ++q) {
      float m = fmaxf(c0[q], c1[q]);
      float e0 = exp_f32_cr(__fsub_rn(c0[q], m));
      float e1 = exp_f32_cr(__fsub_rn(c1[q], m));
      float s = __fdiv_rn(e1, __fadd_rn(e0, e1));
      rr[q] = ((u64)(~__float_as_uint(s)) << 32) | (u32)(p0 + q);
    }
    r0 = rr[0]; r1 = rr[1]; r2 = rr[2]; r3 = rr[3];
  }

  for (int k = 2; k <= NPRI; k <<= 1) {
    if (k >= 512) {
      sk[p0 + 0] = r0; sk[p0 + 1] = r1; sk[p0 + 2] = r2; sk[p0 + 3] = r3;
      __syncthreads();
      for (int j = k >> 1; j >= 256; j >>= 1) {
#pragma unroll
        for (int e = 0; e < 4; ++e) {
          int i = t + (e << 10);
          int ixj = i ^ j;
          if (ixj > i) {
            u64 A = sk[i], B = sk[ixj];
            bool up = ((i & k) == 0);
            if ((A > B) == up) { sk[i] = B; sk[ixj] = A; }
          }
        }
        __syncthreads();
      }
      r0 = sk[p0 + 0]; r1 = sk[p0 + 1]; r2 = sk[p0 + 2]; r3 = sk[p0 + 3];
    }
    {
      bool up = ((p0 & k) == 0);
      for (int j = ((k >> 1) > 128 ? 128 : (k >> 1)); j >= 4; j >>= 1) {
        int m = j >> 2;
        bool lower = ((lane & m) == 0);
        bool takeMin = (lower == up);
        u64 o0 = shflx64(r0, m), o1 = shflx64(r1, m);
        u64 o2 = shflx64(r2, m), o3 = shflx64(r3, m);
        r0 = takeMin ? (r0 < o0 ? r0 : o0) : (r0 > o0 ? r0 : o0);
        r1 = takeMin ? (r1 < o1 ? r1 : o1) : (r1 > o1 ? r1 : o1);
        r2 = takeMin ? (r2 < o2 ? r2 : o2) : (r2 > o2 ? r2 : o2);
        r3 = takeMin ? (r3 < o3 ? r3 : o3) : (r3 > o3 ? r3 : o3);
      }
    }
    if (k >= 4) {
      bool up = ((p0 & k) == 0);
      cmpex(r0, r2, up); cmpex(r1, r3, up);
    }
    if (k == 2) {
      cmpex(r0, r1, true); cmpex(r2, r3, false);
    } else {
      bool up = ((p0 & k) == 0);
      cmpex(r0, r1, up); cmpex(r2, r3, up);
    }
  }

  float* sx1 = ws;
  float* sy1 = ws + 1 * WS_SOA;
  float* sx2 = ws + 2 * WS_SOA;
  float* sy2 = ws + 3 * WS_SOA;
  float* sar = ws + 4 * WS_SOA;
  float* ssc = ws + 5 * WS_SOA;

  u64 keys[4] = {r0, r1, r2, r3};
#pragma unroll
  for (int q = 0; q < 4; ++q) {
    u64 key = keys[q];
    int i = (int)(u32)key;
    float s = __uint_as_float(~(u32)(key >> 32));
    float4 l = ((const float4*)loc)[b * NPRI + i];
    float4 p = ((const float4*)prior)[i];
    float cx = __fadd_rn(p.x, __fmul_rn(__fmul_rn(l.x, 0.1f), p.z));
    float cy = __fadd_rn(p.y, __fmul_rn(__fmul_rn(l.y, 0.1f), p.w));
    float w  = __fmul_rn(p.z, exp_f32_cr(__fmul_rn(l.z, 0.2f)));
    float h  = __fmul_rn(p.w, exp_f32_cr(__fmul_rn(l.w, 0.2f)));
    float hw = __fmul_rn(w, 0.5f), hh = __fmul_rn(h, 0.5f);
    float x1 = __fsub_rn(cx, hw), x2 = __fadd_rn(cx, hw);
    float y1 = __fsub_rn(cy, hh), y2 = __fadd_rn(cy, hh);
    int o = b * NPRI + p0 + q;
    sx1[o] = x1; sy1[o] = y1; sx2[o] = x2; sy2[o] = y2;
    sar[o] = __fmul_rn(__fsub_rn(x2, x1), __fsub_rn(y2, y1));
    ssc[o] = s;
  }
}

// ---------------------------------------------------------------------------
// K2: lazy-mask greedy NMS. One block (4 waves) per image, no mask array.
// Per chunk c (64 candidates):
//   phase 1: removed word = OR over kept-so-far list (LDS) of IoU>th, 4-way
//            wave split + ballot
//   phase 2: 64x64 diagonal block, 16 rows/wave via ballot -> LDS
//   phase 3: wave-0 serial resolve (verified bit logic), append kept to LDS
// Work ~ (Kcum+64)*64 pairs/chunk, early-exit at 200 kept.
// ---------------------------------------------------------------------------
__global__ __launch_bounds__(256) void nms_scan_kernel(const float* __restrict__ ws,
                                                       float* __restrict__ out) {
  __shared__ float4 kbox[TOPK];
  __shared__ float  karea[TOPK];
  __shared__ float4 bx[64];
  __shared__ float  ba[64];
  __shared__ u64 diag[64];
  __shared__ u64 parts[4];
  __shared__ int klist[TOPK];
  __shared__ int s_kcnt, s_cnt, s_stop, s_total;

  const int b = blockIdx.x, t = threadIdx.x, lane = t & 63, wv = t >> 6;
  const float* sx1 = ws;
  const float* sy1 = ws + 1 * WS_SOA;
  const float* sx2 = ws + 2 * WS_SOA;
  const float* sy2 = ws + 3 * WS_SOA;
  const float* sar = ws + 4 * WS_SOA;
  const float* ssc = ws + 5 * WS_SOA;
  // exact threshold: fl(inter/uni) > 0.45f  <=>  inter > M*uni (exact in f64)
  const double M = 0.5 * ((double)0.45f + (double)__uint_as_float(0x3EE66667u));

  if (t == 0) { s_kcnt = 0; s_cnt = 0; s_stop = 0; s_total = 0; }
  __syncthreads();

  for (int c = 0; c < 64; ++c) {
    const int col = c * 64 + lane, o = b * NPRI + col;
    const float x1 = sx1[o], y1 = sy1[o], x2 = sx2[o], y2 = sy2[o], ar = sar[o];
    const int kcnt = s_kcnt;  // stable since previous chunk's final barrier
    if (wv == 0) { bx[lane] = make_float4(x1, y1, x2, y2); ba[lane] = ar; }
    __syncthreads();

    // phase 1: suppression of my column by previously-kept boxes
    bool supp = false;
    for (int k = wv; k < kcnt; k += 4) {
      float4 kb = kbox[k]; float ka = karea[k];
      float iw = fmaxf(__fsub_rn(fminf(kb.z, x2), fmaxf(kb.x, x1)), 0.0f);
      float ih = fmaxf(__fsub_rn(fminf(kb.w, y2), fmaxf(kb.y, y1)), 0.0f);
      float inter = __fmul_rn(iw, ih);
      float uni   = __fsub_rn(__fadd_rn(ka, ar), inter);
      if ((double)inter > M * (double)uni) { supp = true; break; }
    }
    u64 bw = __ballot(supp);
    if (lane == 0) parts[wv] = bw;

    // phase 2: diagonal rows 16wv..16wv+15 (row r vs all 64 cols of chunk)
#pragma unroll 4
    for (int r = 16 * wv; r < 16 * wv + 16; ++r) {
      float4 rb = bx[r]; float ra = ba[r];
      float iw = fmaxf(__fsub_rn(fminf(rb.z, x2), fmaxf(rb.x, x1)), 0.0f);
      float ih = fmaxf(__fsub_rn(fminf(rb.w, y2), fmaxf(rb.y, y1)), 0.0f);
      float inter = __fmul_rn(iw, ih);
      float uni   = __fsub_rn(__fadd_rn(ra, ar), inter);
      u64 dw = __ballot((double)inter > M * (double)uni);
      if (lane == 0) diag[r] = dw;
    }
    __syncthreads();

    // phase 3: serial resolve (wave 0)
    if (wv == 0) {
      float sc = ssc[o];
      u64 vm = __ballot(sc > 0.01f);
      int cnt = s_cnt;
      bool stop = false;
      if (vm == 0) {
        stop = true;  // sorted desc: nothing valid beyond here
      } else {
        u64 rw = parts[0] | parts[1] | parts[2] | parts[3];
        u64 ck = 0;
        for (int g = 0; g < 64; g += 8) {
          u64 d[8];
#pragma unroll
          for (int q = 0; q < 8; ++q) d[q] = diag[g + q];
#pragma unroll
          for (int q = 0; q < 8; ++q) {
            u64 kbit = ((vm & ~rw) >> (g + q)) & 1ull;
            rw |= d[q] & (0ull - kbit);
            ck |= kbit << (g + q);
          }
        }
        if ((ck >> lane) & 1ull) {
          int pos = cnt + __popcll(ck & ((1ull << lane) - 1ull));
          if (pos < TOPK) {
            klist[pos] = col;
            kbox[pos] = make_float4(x1, y1, x2, y2);
            karea[pos] = ar;
          }
        }
        cnt += __popcll(ck);
        if (cnt >= TOPK) stop = true;
      }
      if (lane == 0) {
        int capped = cnt < TOPK ? cnt : TOPK;
        s_kcnt = capped; s_cnt = cnt; s_total = capped; s_stop = stop ? 1 : 0;
      }
    }
    __syncthreads();
    if (s_stop) break;
  }

  const int total = s_total;
  for (int p = t; p < total; p += 256) {
    int i = klist[p];
    int o = b * NPRI + i;
    float* dst = out + (((size_t)b * 2 + 1) * TOPK + p) * 5;
    dst[0] = ssc[o]; dst[1] = sx1[o]; dst[2] = sy1[o]; dst[3] = sx2[o]; dst[4] = sy2[o];
  }
}

// ---------------------------------------------------------------------------
extern "C" void kernel_launch(void* const* d_in, const int* in_sizes, int n_in,
                              void* d_out, int out_size, void* d_ws, size_t ws_size,
                              hipStream_t stream) {
  const float* loc   = (const float*)d_in[0];
  const float* conf  = (const float*)d_in[1];
  const float* prior = (const float*)d_in[2];
  float* out = (float*)d_out;
  float* ws  = (float*)d_ws;

  hipMemsetAsync(d_out, 0, (size_t)out_size * sizeof(float), stream);
  sort_decode_kernel<<<BATCH, 1024, 0, stream>>>(loc, conf, prior, ws);
  nms_scan_kernel<<<BATCH, 256, 0, stream>>>(ws, out);
}